// Round 1
// 3484.707 us; speedup vs baseline: 1.1216x; 1.1216x over previous
//
#include <hip/hip_runtime.h>
#include <hip/hip_bf16.h>

// =====================================================================
// PC-RNN on MI355X.
//   Wq = Wo^T Wo (precomputed);  u_t = (b_o - x_t) @ Wo (parallel GEMM)
// Loop step:  th=tanh(h); h_prior=0.9h+0.1(th@Wr^T + c@Wc^T + b_r)
//             tp=tanh(h_prior); g=tp@Wq+u_t; e=0.1(1-tp^2)g; h=h_prior-e
//             c -= 0.1 e@Wc;  store tp (errors GEMM post-loop)
// Sharding: 32 row-groups x 8 members (64-state slice each); weights
// LDS-resident (158KB -> 1 block/CU).
//
// R4 sync design: FLAG-FREE. Every exchanged word is self-validating:
//  - th/tp are tanh outputs, |v|<=1 -> bf16 exp<=127 -> bit14==0 always.
//    A 1-bit step-parity tag lives in bit14 of EVERY bf16 element
//    (zero precision cost); consumers poll the data words directly and
//    mask bit14 off. Mixed-age halves of an 8B load are detected
//    per-element, so store granularity doesn't matter.
//  - dc words (2xf32) carry the parity in each mantissa LSB (2^-23).
// Single-buffer WAR safety: publish of generation g+1 is transitively
// ordered after every peer's read of generation g (tag-gated poll ->
// intra-block barrier [loads complete] -> publish), and per-location
// coherence monotonicity + alternating parity rule out stale matches.
// Zero-init (tag 0) vs first publish (tag 1) covers step 0; dc zero-init
// IS dc(-1)=0. Removes flag stores, flag polls, and 2 of 6 barriers/step.
// dc partial now via 2 MFMAs (bf16 e) instead of 64-iter scalar loop.
// =====================================================================

#define TSEQ 512
#define NBAT 256
#define NOUT 256
#define NCAU 64
#define NST  512

typedef __attribute__((ext_vector_type(8))) short short8;
typedef __attribute__((ext_vector_type(4))) float floatx4;
typedef unsigned long long ull;

__device__ __forceinline__ unsigned short f2b(float f) {
    union { float f; unsigned u; } v; v.f = f;
    unsigned r = v.u + 0x7FFFu + ((v.u >> 16) & 1u);
    return (unsigned short)(r >> 16);
}
__device__ __forceinline__ float b2f(unsigned short s) {
    union { unsigned u; float f; } v; v.u = ((unsigned)s) << 16;
    return v.f;
}

#define ATOMIC_ST32(p, v) __hip_atomic_store((p), (v), __ATOMIC_RELAXED, __HIP_MEMORY_SCOPE_AGENT)
#define ATOMIC_ST64(p, v) __hip_atomic_store((p), (v), __ATOMIC_RELAXED, __HIP_MEMORY_SCOPE_AGENT)
#define ATOMIC_LD32(p)    __hip_atomic_load((p), __ATOMIC_RELAXED, __HIP_MEMORY_SCOPE_AGENT)
#define ATOMIC_LD64(p)    __hip_atomic_load((p), __ATOMIC_RELAXED, __HIP_MEMORY_SCOPE_AGENT)

#define THBIT1 0x0001000100010001ull   // bit0 of each 16-bit lane (after >>14)
#define THMASK 0x4000400040004000ull   // bit14 of each 16-bit lane
#define DCBIT  0x0000000100000001ull   // mantissa LSB of each f32 half

// ---------------- ws layout (bytes) ----------------
#define SZ_UTP  ((size_t)TSEQ * NBAT * NST * 2)            // 134,217,728
#define OFF_UTP ((size_t)0)
#define OFF_WQ  (OFF_UTP + SZ_UTP)                         // 512*512*2
#define OFF_THX (OFF_WQ + (size_t)NST * NST * 2)           // [32][8][512] bf16 (tagged)
#define OFF_TPX (OFF_THX + (size_t)32 * 8 * NST * 2)       // [32][8][512] bf16 (tagged)
#define OFF_DCX (OFF_TPX + (size_t)32 * 8 * NST * 2)       // [32][8m][8r][64c] f32 (tagged LSB)
#define SZ_ZERO ((size_t)32 * 8 * NST * 2 * 2 + (size_t)32 * 8 * 8 * 64 * 4)

// ---------------- Wq = Wo^T Wo ----------------
__global__ __launch_bounds__(256) void wq_kernel(const float* __restrict__ w_o,
                                                 unsigned short* __restrict__ wqo) {
    int idx = blockIdx.x * 256 + threadIdx.x;
    int i = idx >> 9, j = idx & 511;
    float s = 0.f;
    for (int o = 0; o < NOUT; ++o)
        s += w_o[(size_t)o * NST + i] * w_o[(size_t)o * NST + j];
    wqo[idx] = f2b(s);
}

// ---------------- u_t = (b_o - x_t) @ Wo ----------------
__global__ __launch_bounds__(256) void u_gemm(const float* __restrict__ x,
                                              const float* __restrict__ w_o,
                                              const float* __restrict__ b_o,
                                              unsigned short* __restrict__ u) {
    __shared__ __align__(16) unsigned short As[64 * 72];
    __shared__ __align__(16) unsigned short Bs[64 * 72];
    const int m0 = blockIdx.x * 64, n0 = blockIdx.y * 64;
    const int tid = threadIdx.x;
    const int w = tid >> 6, l = tid & 63, lm = l & 15, lq = l >> 4;
    floatx4 acc[4] = { {0,0,0,0}, {0,0,0,0}, {0,0,0,0}, {0,0,0,0} };
    for (int k0 = 0; k0 < NOUT; k0 += 64) {
        __syncthreads();
        {
            int r = tid >> 2, kk = (tid & 3) * 16;
            const float* src = x + (size_t)(m0 + r) * NOUT + k0 + kk;
            #pragma unroll
            for (int i = 0; i < 16; ++i)
                As[r * 72 + kk + i] = f2b(b_o[k0 + kk + i] - src[i]);
        }
        {
            int kr = tid >> 2, nn = (tid & 3) * 16;
            const float* src = w_o + (size_t)(k0 + kr) * NST + n0 + nn;
            #pragma unroll
            for (int i = 0; i < 16; ++i)
                Bs[(nn + i) * 72 + kr] = f2b(src[i]);
        }
        __syncthreads();
        #pragma unroll
        for (int kt = 0; kt < 2; ++kt) {
            short8 a = *reinterpret_cast<const short8*>(&As[(w * 16 + lm) * 72 + kt * 32 + lq * 8]);
            #pragma unroll
            for (int nt = 0; nt < 4; ++nt) {
                short8 b = *reinterpret_cast<const short8*>(&Bs[(nt * 16 + lm) * 72 + kt * 32 + lq * 8]);
                acc[nt] = __builtin_amdgcn_mfma_f32_16x16x32_bf16(a, b, acc[nt], 0, 0, 0);
            }
        }
    }
    #pragma unroll
    for (int nt = 0; nt < 4; ++nt)
        #pragma unroll
        for (int q = 0; q < 4; ++q) {
            int row = m0 + w * 16 + lq * 4 + q, col = n0 + nt * 16 + lm;
            u[(size_t)row * NST + col] = f2b(acc[nt][q]);
        }
}

// ---------------- errors = tp@Wo^T + b_o - x ----------------
__global__ __launch_bounds__(256) void err_gemm(const unsigned short* __restrict__ tpA,
                                                const float* __restrict__ w_o,
                                                const float* __restrict__ b_o,
                                                const float* __restrict__ x,
                                                float* __restrict__ out) {
    __shared__ __align__(16) unsigned short As[64 * 72];
    __shared__ __align__(16) unsigned short Bs[64 * 72];
    const int m0 = blockIdx.x * 64, n0 = blockIdx.y * 64;
    const int tid = threadIdx.x;
    const int w = tid >> 6, l = tid & 63, lm = l & 15, lq = l >> 4;
    floatx4 acc[4] = { {0,0,0,0}, {0,0,0,0}, {0,0,0,0}, {0,0,0,0} };
    for (int k0 = 0; k0 < NST; k0 += 64) {
        __syncthreads();
        {
            int r = tid >> 2, kk = (tid & 3) * 16;
            const uint4* src = reinterpret_cast<const uint4*>(tpA + (size_t)(m0 + r) * NST + k0 + kk);
            uint4* dst = reinterpret_cast<uint4*>(&As[r * 72 + kk]);
            dst[0] = src[0]; dst[1] = src[1];
        }
        {
            int nr = tid >> 2, kk = (tid & 3) * 16;
            const float* src = w_o + (size_t)(n0 + nr) * NST + k0 + kk;
            #pragma unroll
            for (int i = 0; i < 16; ++i)
                Bs[nr * 72 + kk + i] = f2b(src[i]);
        }
        __syncthreads();
        #pragma unroll
        for (int kt = 0; kt < 2; ++kt) {
            short8 a = *reinterpret_cast<const short8*>(&As[(w * 16 + lm) * 72 + kt * 32 + lq * 8]);
            #pragma unroll
            for (int nt = 0; nt < 4; ++nt) {
                short8 b = *reinterpret_cast<const short8*>(&Bs[(nt * 16 + lm) * 72 + kt * 32 + lq * 8]);
                acc[nt] = __builtin_amdgcn_mfma_f32_16x16x32_bf16(a, b, acc[nt], 0, 0, 0);
            }
        }
    }
    #pragma unroll
    for (int nt = 0; nt < 4; ++nt)
        #pragma unroll
        for (int q = 0; q < 4; ++q) {
            int row = m0 + w * 16 + lq * 4 + q, col = n0 + nt * 16 + lm;
            out[(size_t)row * NOUT + col] = acc[nt][q] + b_o[col] - x[(size_t)row * NOUT + col];
        }
}

// ---------------- persistent sequential loop ----------------
__global__ __launch_bounds__(256, 1) void loop_kernel(
    const float* __restrict__ c_init, const float* __restrict__ h_init,
    const float* __restrict__ w_r, const float* __restrict__ b_r,
    const float* __restrict__ w_c,
    unsigned short* __restrict__ utp, const unsigned short* __restrict__ wq,
    unsigned short* __restrict__ thx, unsigned short* __restrict__ tpx,
    float* __restrict__ dcx) {
    __shared__ __align__(16) short wrF[32768];
    __shared__ __align__(16) short wqF[32768];
    __shared__ __align__(16) short wcF[4096];            // B[col=state][k=cause]  (M1 c-term)
    __shared__ __align__(16) unsigned short wcD[4096];   // B[k=state][col=cause]  (dc MFMA)
    __shared__ __align__(16) unsigned short stage[8 * 520];
    __shared__ __align__(16) unsigned short eS[8 * 72];  // bf16 e_h slice
    __shared__ __align__(16) unsigned short cS[8 * 72];

    const int tid = threadIdx.x;
    const int bid = blockIdx.x;
    const int member = bid & 7;     // 64-state slice within group
    const int grp = bid >> 3;       // row-group [0,32): rows grp*8..grp*8+7
    const int rows0 = grp * 8;
    const int w = tid >> 6, l = tid & 63, lm = l & 15, lq = l >> 4;
    const int jloc = w * 16 + lm;
    const int jglob = member * 64 + jloc;
    const int row8 = tid >> 5, ch = tid & 31, cc = (tid * 2) & 63;  // ch == cc>>1

    unsigned* thxU32 = (unsigned*)thx;
    ull*      thxU64 = (ull*)thx;
    unsigned* tpxU32 = (unsigned*)tpx;
    ull*      tpxU64 = (ull*)tpx;
    unsigned* utpU32 = (unsigned*)utp;
    ull*      dcU64  = (ull*)dcx;

    // ---- prologue: format weights into B-fragment layout in LDS ----
    for (int idx = tid; idx < 4096; idx += 256) {
        int lane = idx & 63, kt = (idx >> 6) & 15, nt = idx >> 10;
        int s0 = member * 64 + nt * 16 + (lane & 15);
        int k = kt * 32 + (lane >> 4) * 8;
        const float* src = w_r + (size_t)s0 * NST + k;
        short8 v;
        #pragma unroll
        for (int jj = 0; jj < 8; ++jj) v[jj] = (short)f2b(src[jj]);
        *reinterpret_cast<short8*>(&wrF[((nt * 16 + kt) * 64 + lane) * 8]) = v;
        short8 v2 = *reinterpret_cast<const short8*>(wq + (size_t)s0 * NST + k);
        *reinterpret_cast<short8*>(&wqF[((nt * 16 + kt) * 64 + lane) * 8]) = v2;
    }
    for (int idx = tid; idx < 512; idx += 256) {
        int lane = idx & 63, kt2 = (idx >> 6) & 1, wv = idx >> 7;
        {
            int j = member * 64 + wv * 16 + (lane & 15);
            int k = kt2 * 32 + (lane >> 4) * 8;
            const float* src = w_c + (size_t)j * NCAU + k;
            short8 v;
            #pragma unroll
            for (int jj = 0; jj < 8; ++jj) v[jj] = (short)f2b(src[jj]);
            *reinterpret_cast<short8*>(&wcF[((wv * 2 + kt2) * 64 + lane) * 8]) = v;
        }
        {
            int cause = wv * 16 + (lane & 15);
            int k = kt2 * 32 + (lane >> 4) * 8;
            short8 v;
            #pragma unroll
            for (int jj = 0; jj < 8; ++jj)
                v[jj] = (short)f2b(w_c[(size_t)(member * 64 + k + jj) * NCAU + cause]);
            *reinterpret_cast<short8*>(&wcD[((wv * 2 + kt2) * 64 + lane) * 8]) = v;
        }
    }

    const float br_l = b_r[jglob];
    float hP[4] = {0.f, 0.f, 0.f, 0.f};
    if (l < 32) {
        #pragma unroll
        for (int q = 0; q < 4; ++q)
            hP[q] = h_init[(size_t)(rows0 + lq * 4 + q) * NST + jglob];
    }
    float cM0 = c_init[(size_t)(rows0 + row8) * NCAU + cc];
    float cM1 = c_init[(size_t)(rows0 + row8) * NCAU + cc + 1];

    // ---- publish th(0), tag=1 (distinct from zero-init tag 0) ----
    {
        unsigned pk[4];
        #pragma unroll
        for (int q = 0; q < 4; ++q) {
            unsigned m_ = f2b(tanhf(hP[q]));
            unsigned p_ = __shfl_xor(m_, 1);
            pk[q] = (m_ | (p_ << 16)) | 0x40004000u;
        }
        if (l < 32 && !(l & 1)) {
            #pragma unroll
            for (int q = 0; q < 4; ++q)
                ATOMIC_ST32(thxU32 + (size_t)grp * 2048 + (lq * 4 + q) * 256 + (jglob >> 1), pk[q]);
        }
    }

    for (int s = 0; s < TSEQ; ++s) {
        // u prefetch (own slice; load completes at barrier (1)'s vmcnt drain,
        // strictly before this thread's later tp store to the same address)
        float uR[4] = {0.f, 0.f, 0.f, 0.f};
        if (l < 32) {
            #pragma unroll
            for (int q = 0; q < 4; ++q)
                uR[q] = b2f(utp[((size_t)(s * NBAT + rows0 + lq * 4 + q)) * NST + jglob]);
        }

        const ull thPat = ((s + 1) & 1) ? THBIT1 : 0ull;   // th(s) and tp(s) parity
        const ull dcPat = (s & 1) ? DCBIT : 0ull;          // dc(s-1) parity

        // ---- A: poll th(s) + dc(s-1) directly (per-element tags) ----
        ull tv[4], dv[8];
        {
            ull* srcT = thxU64 + (size_t)grp * 1024 + row8 * 128 + ch * 4;
            for (;;) {
                bool ok = true;
                #pragma unroll
                for (int i = 0; i < 4; ++i) tv[i] = ATOMIC_LD64(srcT + i);
                #pragma unroll
                for (int m = 0; m < 8; ++m)
                    dv[m] = ATOMIC_LD64(dcU64 + (size_t)(grp * 8 + m) * 256 + row8 * 32 + ch);
                #pragma unroll
                for (int i = 0; i < 4; ++i) ok &= (((tv[i] >> 14) & THBIT1) == thPat);
                #pragma unroll
                for (int m = 0; m < 8; ++m) ok &= ((dv[m] & DCBIT) == dcPat);
                if (ok) break;
                __builtin_amdgcn_s_sleep(1);
            }
        }
        {
            float d0 = 0.f, d1 = 0.f;
            #pragma unroll
            for (int m = 0; m < 8; ++m) {
                union { ull u; float f[2]; } cv; cv.u = dv[m] & ~DCBIT;
                d0 += cv.f[0]; d1 += cv.f[1];
            }
            cM0 -= 0.1f * d0; cM1 -= 0.1f * d1;
            cS[row8 * 72 + cc] = f2b(cM0);
            cS[row8 * 72 + cc + 1] = f2b(cM1);
            ull* dst = reinterpret_cast<ull*>(&stage[row8 * 520 + ch * 16]);
            #pragma unroll
            for (int i = 0; i < 4; ++i) dst[i] = tv[i] & ~THMASK;
        }
        __syncthreads();                                   // (1)

        // ---- M1: h_prior slice = 0.9h + 0.1(th@Wr^T + c@Wc^T + b_r) ----
        floatx4 ac0 = {0.f, 0.f, 0.f, 0.f}, ac1 = {0.f, 0.f, 0.f, 0.f};
        #pragma unroll
        for (int kt = 0; kt < 16; kt += 2) {
            short8 a0 = {0, 0, 0, 0, 0, 0, 0, 0};
            if (lm < 8) a0 = *reinterpret_cast<const short8*>(&stage[lm * 520 + kt * 32 + lq * 8]);
            short8 b0 = *reinterpret_cast<const short8*>(&wrF[((w * 16 + kt) * 64 + l) * 8]);
            ac0 = __builtin_amdgcn_mfma_f32_16x16x32_bf16(a0, b0, ac0, 0, 0, 0);
            short8 a1 = {0, 0, 0, 0, 0, 0, 0, 0};
            if (lm < 8) a1 = *reinterpret_cast<const short8*>(&stage[lm * 520 + (kt + 1) * 32 + lq * 8]);
            short8 b1 = *reinterpret_cast<const short8*>(&wrF[((w * 16 + kt + 1) * 64 + l) * 8]);
            ac1 = __builtin_amdgcn_mfma_f32_16x16x32_bf16(a1, b1, ac1, 0, 0, 0);
        }
        {
            short8 a0 = {0, 0, 0, 0, 0, 0, 0, 0};
            if (lm < 8) a0 = *reinterpret_cast<const short8*>(&cS[lm * 72 + lq * 8]);
            short8 b0 = *reinterpret_cast<const short8*>(&wcF[((w * 2) * 64 + l) * 8]);
            ac0 = __builtin_amdgcn_mfma_f32_16x16x32_bf16(a0, b0, ac0, 0, 0, 0);
            short8 a1 = {0, 0, 0, 0, 0, 0, 0, 0};
            if (lm < 8) a1 = *reinterpret_cast<const short8*>(&cS[lm * 72 + 32 + lq * 8]);
            short8 b1 = *reinterpret_cast<const short8*>(&wcF[((w * 2 + 1) * 64 + l) * 8]);
            ac1 = __builtin_amdgcn_mfma_f32_16x16x32_bf16(a1, b1, ac1, 0, 0, 0);
        }
        float hPr[4], tp[4];
        #pragma unroll
        for (int q = 0; q < 4; ++q) {
            float av = ac0[q] + ac1[q];
            hPr[q] = 0.9f * hP[q] + 0.1f * (av + br_l);
            tp[q] = tanhf(hPr[q]);
        }

        // ---- publish tp(s): tagged -> tpx (peers poll), clean -> utp[s] (err_gemm) ----
        {
            const unsigned tb = ((s + 1) & 1) ? 0x40004000u : 0u;
            unsigned pk[4];
            #pragma unroll
            for (int q = 0; q < 4; ++q) {
                unsigned m_ = f2b(tp[q]);
                unsigned p_ = __shfl_xor(m_, 1);
                pk[q] = m_ | (p_ << 16);
            }
            if (l < 32 && !(l & 1)) {
                #pragma unroll
                for (int q = 0; q < 4; ++q) {
                    ATOMIC_ST32(tpxU32 + (size_t)grp * 2048 + (lq * 4 + q) * 256 + (jglob >> 1), pk[q] | tb);
                    ATOMIC_ST32(utpU32 + ((size_t)(s * NBAT) + rows0 + lq * 4 + q) * 256 + (jglob >> 1), pk[q]);
                }
            }
        }
        __syncthreads();                                   // (2) stage readers done

        // ---- B: poll tp(s) ----
        {
            ull pv[4];
            ull* srcP = tpxU64 + (size_t)grp * 1024 + row8 * 128 + ch * 4;
            for (;;) {
                bool ok = true;
                #pragma unroll
                for (int i = 0; i < 4; ++i) pv[i] = ATOMIC_LD64(srcP + i);
                #pragma unroll
                for (int i = 0; i < 4; ++i) ok &= (((pv[i] >> 14) & THBIT1) == thPat);
                if (ok) break;
                __builtin_amdgcn_s_sleep(1);
            }
            ull* dst = reinterpret_cast<ull*>(&stage[row8 * 520 + ch * 16]);
            #pragma unroll
            for (int i = 0; i < 4; ++i) dst[i] = pv[i] & ~THMASK;
        }
        __syncthreads();                                   // (3)

        // ---- M2: g slice = tp@Wq + u_t ----
        floatx4 g0 = {0.f, 0.f, 0.f, 0.f}, g1 = {0.f, 0.f, 0.f, 0.f};
        #pragma unroll
        for (int kt = 0; kt < 16; kt += 2) {
            short8 a0 = {0, 0, 0, 0, 0, 0, 0, 0};
            if (lm < 8) a0 = *reinterpret_cast<const short8*>(&stage[lm * 520 + kt * 32 + lq * 8]);
            short8 b0 = *reinterpret_cast<const short8*>(&wqF[((w * 16 + kt) * 64 + l) * 8]);
            g0 = __builtin_amdgcn_mfma_f32_16x16x32_bf16(a0, b0, g0, 0, 0, 0);
            short8 a1 = {0, 0, 0, 0, 0, 0, 0, 0};
            if (lm < 8) a1 = *reinterpret_cast<const short8*>(&stage[lm * 520 + (kt + 1) * 32 + lq * 8]);
            short8 b1 = *reinterpret_cast<const short8*>(&wqF[((w * 16 + kt + 1) * 64 + l) * 8]);
            g1 = __builtin_amdgcn_mfma_f32_16x16x32_bf16(a1, b1, g1, 0, 0, 0);
        }
        float eH[4];
        #pragma unroll
        for (int q = 0; q < 4; ++q) {
            float g = g0[q] + g1[q] + uR[q];
            eH[q] = 0.1f * (1.f - tp[q] * tp[q]) * g;
            hP[q] = hPr[q] - eH[q];
        }

        // ---- publish th(s+1) EARLY (tag = s&1), before dc work ----
        {
            const unsigned tb = (s & 1) ? 0x40004000u : 0u;
            unsigned pk[4];
            #pragma unroll
            for (int q = 0; q < 4; ++q) {
                unsigned m_ = f2b(tanhf(hP[q]));
                unsigned p_ = __shfl_xor(m_, 1);
                pk[q] = (m_ | (p_ << 16)) | tb;
            }
            if (l < 32 && !(l & 1)) {
                #pragma unroll
                for (int q = 0; q < 4; ++q)
                    ATOMIC_ST32(thxU32 + (size_t)grp * 2048 + (lq * 4 + q) * 256 + (jglob >> 1), pk[q]);
            }
        }
        if (l < 32) {
            #pragma unroll
            for (int q = 0; q < 4; ++q) eS[(lq * 4 + q) * 72 + jloc] = f2b(eH[q]);
        }
        __syncthreads();                                   // (4)

        // ---- dc(s) = e_h(slice) @ Wc(slice) via 2 MFMAs; publish tagged ----
        floatx4 ac3 = {0.f, 0.f, 0.f, 0.f};
        #pragma unroll
        for (int kt = 0; kt < 2; ++kt) {
            short8 a = {0, 0, 0, 0, 0, 0, 0, 0};
            if (lm < 8) a = *reinterpret_cast<const short8*>(&eS[lm * 72 + kt * 32 + lq * 8]);
            short8 b = *reinterpret_cast<const short8*>(&wcD[((w * 2 + kt) * 64 + l) * 8]);
            ac3 = __builtin_amdgcn_mfma_f32_16x16x32_bf16(a, b, ac3, 0, 0, 0);
        }
        {
            const ull dp = ((s + 1) & 1) ? DCBIT : 0ull;
            #pragma unroll
            for (int q = 0; q < 4; ++q) {
                float o = __shfl_xor(ac3[q], 1);
                if (!(l & 1) && lq < 2) {
                    union { float f[2]; ull u; } pv2;
                    pv2.f[0] = ac3[q]; pv2.f[1] = o;
                    pv2.u = (pv2.u & ~DCBIT) | dp;
                    ATOMIC_ST64(dcU64 + (size_t)(grp * 8 + member) * 256 + (lq * 4 + q) * 32 + w * 8 + (lm >> 1), pv2.u);
                }
            }
        }
        // no barrier needed here: next A-phase touches stage/cS only, both
        // already separated from this iteration's readers by barrier (4).
    }
}

extern "C" void kernel_launch(void* const* d_in, const int* in_sizes, int n_in,
                              void* d_out, int out_size, void* d_ws, size_t ws_size,
                              hipStream_t stream) {
    const float* x      = (const float*)d_in[0];
    const float* c_init = (const float*)d_in[1];
    const float* h_init = (const float*)d_in[2];
    const float* w_o    = (const float*)d_in[3];
    const float* b_o    = (const float*)d_in[4];
    const float* w_c    = (const float*)d_in[5];
    const float* w_r    = (const float*)d_in[6];
    const float* b_r    = (const float*)d_in[7];

    char* wsb = (char*)d_ws;
    unsigned short* utp = (unsigned short*)(wsb + OFF_UTP);
    unsigned short* wq  = (unsigned short*)(wsb + OFF_WQ);
    unsigned short* thx = (unsigned short*)(wsb + OFF_THX);
    unsigned short* tpx = (unsigned short*)(wsb + OFF_TPX);
    float*          dcx = (float*)(wsb + OFF_DCX);

    hipMemsetAsync(wsb + OFF_THX, 0, SZ_ZERO, stream);

    wq_kernel<<<dim3((NST * NST) / 256), dim3(256), 0, stream>>>(w_o, wq);
    u_gemm<<<dim3((TSEQ * NBAT) / 64, NST / 64), dim3(256), 0, stream>>>(x, w_o, b_o, utp);

    void* args[] = { (void*)&c_init, (void*)&h_init, (void*)&w_r, (void*)&b_r,
                     (void*)&w_c, (void*)&utp, (void*)&wq, (void*)&thx,
                     (void*)&tpx, (void*)&dcx };
    hipLaunchCooperativeKernel((void*)loop_kernel, dim3(256), dim3(256), args, 0, stream);

    err_gemm<<<dim3((TSEQ * NBAT) / 64, NOUT / 64), dim3(256), 0, stream>>>(utp, w_o, b_o, x, (float*)d_out);
}